// Round 12
// baseline (32.466 us; speedup 1.0000x reference)
//
#include <hip/hip_runtime.h>

#define RS 7
#define SR 2
#define PD 10
#define CH (PD * RS * RS)   // 490
#define SCALE (1.0f / 16.0f)
#define HH 100
#define WW 100
#define NPLANE (HH * WW)    // 10000
#define PADP 104            // pad floats (max index o+WW+1 = 10100)
#define BUFSZ (NPLANE + PADP)
#define MAXN 4096
#define TPB 1024
#define NBLK 256
#define SLICE 245           // tiles (cins) per XCD slice: 1960/8

// ---- async global->LDS, 16B per lane, NT (no L2 allocate: CPol bit1) ----
__device__ __forceinline__ void gll16_nt(const void* g, void* l) {
    __builtin_amdgcn_global_load_lds(
        (const __attribute__((address_space(1))) void*)g,
        (__attribute__((address_space(3))) void*)l, 16, 0, 2 /*nt*/);
}

// ---- persistent streaming kernel: 256 blocks (1/CU), dbuf fp32 planes ----
__global__ __launch_bounds__(TPB) void psroi_stream_kernel(
    const float* __restrict__ feat, const float* __restrict__ rois,
    float* __restrict__ out, int N)
{
    __shared__ __align__(16) float buf0[BUFSZ];   // 40.4 KB
    __shared__ __align__(16) float buf1[BUFSZ];   // 40.4 KB
    __shared__ unsigned short list[MAXN];         // 8 KB
    __shared__ int lcnt;

    int tid = threadIdx.x;
    int bid = blockIdx.x;
    int xcd = bid & 7;          // heuristic XCD id (perf-only)
    int j   = bid >> 3;         // 0..31 within XCD
    int b   = xcd >> 1;         // one batch per slice: 1960 = 4b x 490, 490 = 2x245
    int cin0 = (xcd & 1) * SLICE + j;    // this block's k-th tile: cin0 + k*32
    int ntile = (SLICE - 1 - j) / 32 + 1; // 7 or 8 tiles

    // zero the pad rows of both buffers; init list count
    if (tid < PADP) { buf0[NPLANE + tid] = 0.0f; buf1[NPLANE + tid] = 0.0f; }
    if (tid == 0) lcnt = 0;
    __syncthreads();

    // stage a tile via NT DMA (issues immediately; latency hidden under scan/compute)
    auto stage = [&](float* dst, int cin) {
        const char* gs = (const char*)(feat + (size_t)(b * CH + cin) * NPLANE);
        char* ls = (char*)dst;
        int wbase = tid & ~63;                       // wave-uniform LDS base
        #pragma unroll
        for (int c = 0; c < 3; ++c) {
            int slot = c * TPB + tid;
            if (slot < NPLANE / 4)                   // 2500 16B slots
                gll16_nt(gs + (size_t)slot * 16, ls + (size_t)(c * TPB + wbase) * 16);
        }
    };
    stage(buf0, cin0);

    // build ROI list for this slice's batch (once per block), under DMA latency
    {
        int lane = tid & 63;
        for (int k0 = 0; k0 < N; k0 += TPB) {
            int k = k0 + tid;
            bool m = (k < N) && ((int)rois[(size_t)k * 5] == b);
            unsigned long long msk = __ballot(m);
            if (m) {
                int rank   = __popcll(msk & ((1ull << lane) - 1ull));
                int leader = __ffsll((long long)msk) - 1;
                int pos = 0;
                if (lane == leader) pos = atomicAdd(&lcnt, (int)__popcll(msk));
                pos = __shfl(pos, leader);
                list[pos + rank] = (unsigned short)k;
            }
        }
    }
    __syncthreads();   // drain DMA (vmcnt) + make list visible

    for (int k = 0; k < ntile; ++k) {
        const float* __restrict__ bc = (k & 1) ? buf1 : buf0;
        float* bn = (k & 1) ? buf0 : buf1;
        int cin = cin0 + k * 32;
        if (k + 1 < ntile) stage(bn, cin + 32);      // next tile's DMA in flight
        __builtin_amdgcn_sched_barrier(0);           // keep issue before compute

        int pw = cin % RS;
        int ph = (cin / RS) % RS;
        int cnt = lcnt;
        for (int i = tid; i < cnt; i += TPB) {
            int n = list[i];
            const float* rp = rois + (size_t)n * 5;
            float sw = rp[1] * SCALE - 0.5f;
            float sh = rp[2] * SCALE - 0.5f;
            float bw = (rp[3] * SCALE - 0.5f - sw) * (1.0f / RS);
            float bh = (rp[4] * SCALE - 0.5f - sh) * (1.0f / RS);
            float acc = 0.0f;
            #pragma unroll
            for (int iy = 0; iy < SR; ++iy) {
                float y  = sh + ((float)ph + ((float)iy + 0.5f) * (1.0f / SR)) * bh;
                bool  vy = (y >= -1.0f) && (y <= (float)HH);
                float yy = fmaxf(y, 0.0f);
                int   y0 = min((int)floorf(yy), HH - 1);
                float yc = (y0 >= HH - 1) ? (float)y0 : yy;
                float ly = yc - (float)y0;
                float hy = 1.0f - ly;
                #pragma unroll
                for (int ix = 0; ix < SR; ++ix) {
                    float x  = sw + ((float)pw + ((float)ix + 0.5f) * (1.0f / SR)) * bw;
                    bool  vx = (x >= -1.0f) && (x <= (float)WW);
                    float xx = fmaxf(x, 0.0f);
                    int   x0 = min((int)floorf(xx), WW - 1);
                    float xc = (x0 >= WW - 1) ? (float)x0 : xx;
                    float lx = xc - (float)x0;
                    float hx = 1.0f - lx;
                    // clamp-by-weight: out-of-plane taps land in zeroed pad or
                    // finite neighbor data with exactly-zero weight
                    int o = y0 * WW + x0;
                    float v00 = bc[o],      v01 = bc[o + 1];
                    float v10 = bc[o + WW], v11 = bc[o + WW + 1];
                    float v = hy * (hx * v00 + lx * v01) + ly * (hx * v10 + lx * v11);
                    if (vy && vx) acc += v;
                }
            }
            out[(size_t)n * CH + cin] = acc * (1.0f / (SR * SR));
        }
        __syncthreads();   // drains vmcnt (next tile committed) + all reads done
    }
}

// ---- general fallback (any B / N > MAXN): direct-gather per output ----
__global__ __launch_bounds__(256) void psroi_naive_kernel(
    const float* __restrict__ feat, const float* __restrict__ rois,
    float* __restrict__ out, int total)
{
    int o = blockIdx.x * blockDim.x + threadIdx.x;
    if (o >= total) return;
    int cin = o % CH;
    int n   = o / CH;
    int pw  = cin % RS;
    int ph  = (cin / RS) % RS;
    const float* r = rois + (size_t)n * 5;
    int bidx = (int)r[0];
    float sw = r[1] * SCALE - 0.5f;
    float sh = r[2] * SCALE - 0.5f;
    float bw = (r[3] * SCALE - 0.5f - sw) * (1.0f / RS);
    float bh = (r[4] * SCALE - 0.5f - sh) * (1.0f / RS);
    const float* base = feat + (size_t)(bidx * CH + cin) * NPLANE;
    float acc = 0.0f;
    #pragma unroll
    for (int iy = 0; iy < SR; ++iy) {
        float y  = sh + ((float)ph + ((float)iy + 0.5f) * (1.0f / SR)) * bh;
        bool  vy = (y >= -1.0f) && (y <= (float)HH);
        float yy = fmaxf(y, 0.0f);
        int   y0 = min((int)floorf(yy), HH - 1);
        int   y1 = min(y0 + 1, HH - 1);
        float yc = (y0 >= HH - 1) ? (float)y0 : yy;
        float ly = yc - (float)y0;
        float hy = 1.0f - ly;
        #pragma unroll
        for (int ix = 0; ix < SR; ++ix) {
            float x  = sw + ((float)pw + ((float)ix + 0.5f) * (1.0f / SR)) * bw;
            bool  vx = (x >= -1.0f) && (x <= (float)WW);
            float xx = fmaxf(x, 0.0f);
            int   x0 = min((int)floorf(xx), WW - 1);
            int   x1 = min(x0 + 1, WW - 1);
            float xc = (x0 >= WW - 1) ? (float)x0 : xx;
            float lx = xc - (float)x0;
            float hx = 1.0f - lx;
            float v00 = base[y0 * WW + x0];
            float v01 = base[y0 * WW + x1];
            float v10 = base[y1 * WW + x0];
            float v11 = base[y1 * WW + x1];
            float v = hy * (hx * v00 + lx * v01) + ly * (hx * v10 + lx * v11);
            if (vy && vx) acc += v;
        }
    }
    out[o] = acc * (1.0f / (SR * SR));
}

extern "C" void kernel_launch(void* const* d_in, const int* in_sizes, int n_in,
                              void* d_out, int out_size, void* d_ws, size_t ws_size,
                              hipStream_t stream) {
    const float* feat = (const float*)d_in[0];
    const float* rois = (const float*)d_in[1];
    float* out = (float*)d_out;
    int N = in_sizes[1] / 5;
    int B = in_sizes[0] / (CH * NPLANE);

    if (N <= MAXN && B == 4) {
        psroi_stream_kernel<<<NBLK, TPB, 0, stream>>>(feat, rois, out, N);
    } else {
        int total = N * CH;
        psroi_naive_kernel<<<(total + 255) / 256, 256, 0, stream>>>(feat, rois, out, total);
    }
}

// Round 13
// 26.835 us; speedup vs baseline: 1.2098x; 1.2098x over previous
//
#include <hip/hip_runtime.h>

#define RS 7
#define SR 2
#define PD 10
#define CH (PD * RS * RS)   // 490
#define SCALE (1.0f / 16.0f)
#define HH 100
#define WW 100
#define NPLANE (HH * WW)    // 10000
#define SLOTS 2560          // 16B slots per buffer incl pad (data: 2500)
#define BUFF (SLOTS * 4)    // 10240 floats
#define TPB 1024
#define NBLK 256
#define SLICE 245           // cins per XCD slice (1960/8)
#define CAPR 1536           // LDS param cache entries
#define MAXN 4096

// async global->LDS, 16B per lane; LDS dest is WAVE-UNIFORM base (+lane*16 by HW)
__device__ __forceinline__ void gll16(const void* g, void* l) {
    __builtin_amdgcn_global_load_lds(
        (const __attribute__((address_space(1))) void*)g,
        (__attribute__((address_space(3))) void*)l, 16, 0, 0);
}

__device__ __forceinline__ void waitv(int allowed) {
    switch (allowed) {
        case 0: asm volatile("s_waitcnt vmcnt(0)" ::: "memory"); break;
        case 1: asm volatile("s_waitcnt vmcnt(1)" ::: "memory"); break;
        case 2: asm volatile("s_waitcnt vmcnt(2)" ::: "memory"); break;
        case 3: asm volatile("s_waitcnt vmcnt(3)" ::: "memory"); break;
        case 4: asm volatile("s_waitcnt vmcnt(4)" ::: "memory"); break;
        case 5: asm volatile("s_waitcnt vmcnt(5)" ::: "memory"); break;
        case 6: asm volatile("s_waitcnt vmcnt(6)" ::: "memory"); break;
        case 7: asm volatile("s_waitcnt vmcnt(7)" ::: "memory"); break;
        default: asm volatile("s_waitcnt vmcnt(0)" ::: "memory"); break;
    }
}

// persistent triple-buffered pipeline: 256 blocks (1/CU), 1024 thr, 7-8 tiles/block
__global__ __launch_bounds__(TPB) void psroi_pipe_kernel(
    const float* __restrict__ feat, const float* __restrict__ rois,
    float* __restrict__ out, int N)
{
    __shared__ __align__(16) float buf0[BUFF];    // 40 KB each
    __shared__ __align__(16) float buf1[BUFF];
    __shared__ __align__(16) float buf2[BUFF];
    __shared__ __align__(16) float4 params[CAPR]; // 24 KB
    __shared__ unsigned short list[MAXN];         // 8 KB
    __shared__ int lcnt;

    int tid  = threadIdx.x;
    int wid  = tid >> 6;
    int lane = tid & 63;
    int bid  = blockIdx.x;
    int xcd  = bid & 7;                 // heuristic XCD id (perf-only)
    int j    = bid >> 3;                // 0..31
    int b    = xcd >> 1;                // batch per slice-pair
    int cin0 = (xcd & 1) * SLICE + j;   // tiles: cin0 + k*32
    int ntile = (SLICE - 1 - j) / 32 + 1;

    if (tid == 0) lcnt = 0;
    __syncthreads();

    // ---- 1) scan rois + precompute params (ALL global loads before any DMA) ----
    for (int k0 = 0; k0 < N; k0 += TPB) {
        int k = k0 + tid;
        bool m = (k < N) && ((int)rois[(size_t)k * 5] == b);
        unsigned long long msk = __ballot(m);
        if (m) {
            int rank   = __popcll(msk & ((1ull << lane) - 1ull));
            int leader = __ffsll((long long)msk) - 1;
            int pos = 0;
            if (lane == leader) pos = atomicAdd(&lcnt, (int)__popcll(msk));
            pos = __shfl(pos, leader) + rank;
            list[pos] = (unsigned short)k;
            if (pos < CAPR) {
                const float* rp = rois + (size_t)k * 5;
                float sw = rp[1] * SCALE - 0.5f;
                float sh = rp[2] * SCALE - 0.5f;
                float bw = (rp[3] * SCALE - 0.5f - sw) * (1.0f / RS);
                float bh = (rp[4] * SCALE - 0.5f - sh) * (1.0f / RS);
                params[pos] = make_float4(sw, sh, bw, bh);
            }
        }
    }

    // ---- 2) stage: exactly 3 gll per wave (uniform vmcnt accounting) ----
    auto stage = [&](float* dst, int cin) {
        const char* gs = (const char*)(feat + (size_t)(b * CH + cin) * NPLANE);
        char* ls = (char*)dst;
        int wb = wid << 6;
        gll16(gs + (size_t)(tid) * 16,        ls + (size_t)(wb) * 16);
        gll16(gs + (size_t)(TPB + tid) * 16,  ls + (size_t)(TPB + wb) * 16);
        int s2b = 2048 + ((wid & 7) << 6);              // waves w, w+8 duplicate
        int g2  = min(s2b + lane, 2499);                // clamp: pad gets finite junk
        gll16(gs + (size_t)g2 * 16,           ls + (size_t)s2b * 16);
    };

    stage(buf0, cin0);
    if (ntile > 1) stage(buf1, cin0 + 32);

    asm volatile("s_waitcnt lgkmcnt(0)" ::: "memory");   // scan LDS writes done
    if (ntile > 1) waitv(3); else waitv(0);              // stage(t0) done; t1 in flight
    __builtin_amdgcn_s_barrier();
    __builtin_amdgcn_sched_barrier(0);

    int cnt = lcnt;

    // ---- 3) pipelined tile loop ----
    for (int k = 0; k < ntile; ++k) {
        const float* __restrict__ bc = (k % 3 == 0) ? buf0 : ((k % 3 == 1) ? buf1 : buf2);
        if (k + 2 < ntile) {
            float* bn = ((k + 2) % 3 == 0) ? buf0 : (((k + 2) % 3 == 1) ? buf1 : buf2);
            stage(bn, cin0 + (k + 2) * 32);
        }
        __builtin_amdgcn_sched_barrier(0);               // keep issue before compute

        int cin = cin0 + k * 32;
        int pw  = cin % RS;
        int ph  = (cin / RS) % RS;

        int iters = 0;
        for (int i = tid; i < cnt; i += TPB) {
            ++iters;
            float sw, sh, bw, bh;
            int n;
            if (i < CAPR) {
                float4 p = params[i];                    // LDS (no vmcnt!)
                n = list[i];
                sw = p.x; sh = p.y; bw = p.z; bh = p.w;
            } else {                                     // rare overflow path
                n = list[i];
                const float* rp = rois + (size_t)n * 5;
                sw = rp[1] * SCALE - 0.5f;
                sh = rp[2] * SCALE - 0.5f;
                bw = (rp[3] * SCALE - 0.5f - sw) * (1.0f / RS);
                bh = (rp[4] * SCALE - 0.5f - sh) * (1.0f / RS);
            }
            float acc = 0.0f;
            #pragma unroll
            for (int iy = 0; iy < SR; ++iy) {
                float y  = sh + ((float)ph + ((float)iy + 0.5f) * (1.0f / SR)) * bh;
                bool  vy = (y >= -1.0f) && (y <= (float)HH);
                float yy = fmaxf(y, 0.0f);
                int   y0 = min((int)floorf(yy), HH - 1);
                float yc = (y0 >= HH - 1) ? (float)y0 : yy;
                float ly = yc - (float)y0;
                float hy = 1.0f - ly;
                #pragma unroll
                for (int ix = 0; ix < SR; ++ix) {
                    float x  = sw + ((float)pw + ((float)ix + 0.5f) * (1.0f / SR)) * bw;
                    bool  vx = (x >= -1.0f) && (x <= (float)WW);
                    float xx = fmaxf(x, 0.0f);
                    int   x0 = min((int)floorf(xx), WW - 1);
                    float xc = (x0 >= WW - 1) ? (float)x0 : xx;
                    float lx = xc - (float)x0;
                    float hx = 1.0f - lx;
                    // clamp-by-weight: stray taps (pad/finite junk) carry weight 0
                    int o = y0 * WW + x0;
                    float v00 = bc[o],      v01 = bc[o + 1];
                    float v10 = bc[o + WW], v11 = bc[o + WW + 1];
                    float v = hy * (hx * v00 + lx * v01) + ly * (hx * v10 + lx * v11);
                    if (vy && vx) acc += v;
                }
            }
            out[(size_t)n * CH + cin] = acc * (1.0f / (SR * SR));
        }

        if (k + 1 < ntile) {
            // wait stage(k+1) complete; allow stage(k+2) gll (3) + own stores (iters)
            int allowed = iters + ((k + 2 < ntile) ? 3 : 0);
            waitv(allowed);
            __builtin_amdgcn_s_barrier();
            __builtin_amdgcn_sched_barrier(0);
        }
    }
}

// ---- general fallback (any B / N > MAXN): direct-gather per output ----
__global__ __launch_bounds__(256) void psroi_naive_kernel(
    const float* __restrict__ feat, const float* __restrict__ rois,
    float* __restrict__ out, int total)
{
    int o = blockIdx.x * blockDim.x + threadIdx.x;
    if (o >= total) return;
    int cin = o % CH;
    int n   = o / CH;
    int pw  = cin % RS;
    int ph  = (cin / RS) % RS;
    const float* r = rois + (size_t)n * 5;
    int bidx = (int)r[0];
    float sw = r[1] * SCALE - 0.5f;
    float sh = r[2] * SCALE - 0.5f;
    float bw = (r[3] * SCALE - 0.5f - sw) * (1.0f / RS);
    float bh = (r[4] * SCALE - 0.5f - sh) * (1.0f / RS);
    const float* base = feat + (size_t)(bidx * CH + cin) * NPLANE;
    float acc = 0.0f;
    #pragma unroll
    for (int iy = 0; iy < SR; ++iy) {
        float y  = sh + ((float)ph + ((float)iy + 0.5f) * (1.0f / SR)) * bh;
        bool  vy = (y >= -1.0f) && (y <= (float)HH);
        float yy = fmaxf(y, 0.0f);
        int   y0 = min((int)floorf(yy), HH - 1);
        int   y1 = min(y0 + 1, HH - 1);
        float yc = (y0 >= HH - 1) ? (float)y0 : yy;
        float ly = yc - (float)y0;
        float hy = 1.0f - ly;
        #pragma unroll
        for (int ix = 0; ix < SR; ++ix) {
            float x  = sw + ((float)pw + ((float)ix + 0.5f) * (1.0f / SR)) * bw;
            bool  vx = (x >= -1.0f) && (x <= (float)WW);
            float xx = fmaxf(x, 0.0f);
            int   x0 = min((int)floorf(xx), WW - 1);
            int   x1 = min(x0 + 1, WW - 1);
            float xc = (x0 >= WW - 1) ? (float)x0 : xx;
            float lx = xc - (float)x0;
            float hx = 1.0f - lx;
            float v00 = base[y0 * WW + x0];
            float v01 = base[y0 * WW + x1];
            float v10 = base[y1 * WW + x0];
            float v11 = base[y1 * WW + x1];
            float v = hy * (hx * v00 + lx * v01) + ly * (hx * v10 + lx * v11);
            if (vy && vx) acc += v;
        }
    }
    out[o] = acc * (1.0f / (SR * SR));
}

extern "C" void kernel_launch(void* const* d_in, const int* in_sizes, int n_in,
                              void* d_out, int out_size, void* d_ws, size_t ws_size,
                              hipStream_t stream) {
    const float* feat = (const float*)d_in[0];
    const float* rois = (const float*)d_in[1];
    float* out = (float*)d_out;
    int N = in_sizes[1] / 5;
    int B = in_sizes[0] / (CH * NPLANE);

    if (N <= MAXN && B == 4) {
        psroi_pipe_kernel<<<NBLK, TPB, 0, stream>>>(feat, rois, out, N);
    } else {
        int total = N * CH;
        psroi_naive_kernel<<<(total + 255) / 256, 256, 0, stream>>>(feat, rois, out, total);
    }
}